// Round 1
// 325.034 us; speedup vs baseline: 1.0515x; 1.0515x over previous
//
#include <hip/hip_runtime.h>

typedef unsigned short u16;
typedef unsigned int u32;
typedef __attribute__((ext_vector_type(8))) short short8;
typedef __attribute__((ext_vector_type(4))) float f32x4;

#define HID 128

static inline int cdiv(long long a, int b) { return (int)((a + b - 1) / b); }

__device__ __forceinline__ float bfbits(u32 u) { union { u32 u; float f; } c; c.u = u; return c.f; }
__device__ __forceinline__ u16 f2bf(float f) {
  union { float f; u32 u; } c; c.f = f;
  u32 u = c.u;
  return (u16)((u + 0x7fffu + ((u >> 16) & 1u)) >> 16);  // RNE
}
__device__ __forceinline__ u32 pack2bf(float a, float b) {
  return (u32)f2bf(a) | ((u32)f2bf(b) << 16);
}

// ---------- W pre-transpose + bf16 cast: WT[c][k] = bf16(W[k][c]) ----------
__global__ __launch_bounds__(256) void prep_wt(const float* __restrict__ W,
                                               u16* __restrict__ WT, int cout) {
  int idx = blockIdx.x * 256 + threadIdx.x;
  if (idx < 128 * cout) {
    int k = idx / cout, c = idx - k * cout;
    WT[c * 128 + k] = f2bf(W[idx]);
  }
}

// ---------- MFMA GEMM + attention epilogue ----------
// C_t[col][row] tile via mfma(Wfrag, Hfrag): each lane holds 4 consecutive
// OUTPUT COLUMNS of one node-row -> packed uint2 XL stores, 2-shuffle row
// reduction for attention sums. A/B k-mapping identical => any HW k-order OK.
template <int COUT, int HEADS>
__global__ __launch_bounds__(256) void gemm_attn_mfma(
    const float* __restrict__ Hin, const u16* __restrict__ WT,
    const float* __restrict__ attS, const float* __restrict__ attD,
    u16* __restrict__ XL, float* __restrict__ aS, float* __restrict__ aD, int n) {
  constexpr int BM = 64;          // rows per block
  constexpr int NT = COUT / 16;   // col tiles (8 or 4)
  constexpr int C = COUT / HEADS; // per-head channels
  constexpr int TPH = C / 16;     // tiles per head (2 or 4)

  // pad 128->136 u16 (272B rows): fragment reads become bank-uniform
  __shared__ u16 aT[BM][136];

  int t = threadIdx.x;
  int rowBase = blockIdx.x * BM;

  // ---- stage 64 H-rows fp32 -> bf16 into LDS (coalesced float4 loads) ----
#pragma unroll
  for (int p = 0; p < 8; ++p) {
    int id = p * 256 + t;   // float4 id within 64x128 tile
    int r = id >> 5;        // 32 float4 per row
    int c4 = id & 31;
    int grow = rowBase + r;
    float4 v = make_float4(0.f, 0.f, 0.f, 0.f);
    if (grow < n) v = *(const float4*)(Hin + (size_t)grow * HID + c4 * 4);
    *(uint2*)&aT[r][c4 * 4] = make_uint2(pack2bf(v.x, v.y), pack2bf(v.z, v.w));
  }
  __syncthreads();

  int wv = t >> 6;        // wave id: rows [wv*16, wv*16+16)
  int ln = t & 63;
  int lrow = ln & 15;     // node-row within 16-group (= D col index)
  int lk = ln >> 4;       // k sub-chunk / D row-quad index

  f32x4 acc[NT];
#pragma unroll
  for (int ct = 0; ct < NT; ++ct) acc[ct] = {0.f, 0.f, 0.f, 0.f};

#pragma unroll
  for (int kb = 0; kb < 4; ++kb) {
    // B operand: H rows as cols. 16B LDS read, padded-row => uniform banks.
    short8 bh = *(const short8*)&aT[wv * 16 + lrow][kb * 32 + lk * 8];
    const u16* wp = WT + (size_t)lrow * HID + kb * 32 + lk * 8;
#pragma unroll
    for (int ct = 0; ct < NT; ++ct) {
      // A operand: W^T cols as rows, straight from global (L2-resident 32KB)
      short8 aw = *(const short8*)(wp + (size_t)ct * 16 * HID);
      acc[ct] = __builtin_amdgcn_mfma_f32_16x16x32_bf16(aw, bh, acc[ct], 0, 0, 0);
    }
  }

  int row = rowBase + wv * 16 + lrow;

  // ---- attention epilogue: per-row per-head dots from acc registers ----
  // acc[ct][r] = xl[row][ col = ct*16 + lk*4 + r ]
  float pS[HEADS], pD[HEADS];
#pragma unroll
  for (int h = 0; h < HEADS; ++h) { pS[h] = 0.f; pD[h] = 0.f; }
#pragma unroll
  for (int ct = 0; ct < NT; ++ct) {
    float4 sv = *(const float4*)(attS + ct * 16 + lk * 4);
    float4 dv = *(const float4*)(attD + ct * 16 + lk * 4);
    int h = ct / TPH;
    pS[h] += acc[ct][0] * sv.x + acc[ct][1] * sv.y + acc[ct][2] * sv.z + acc[ct][3] * sv.w;
    pD[h] += acc[ct][0] * dv.x + acc[ct][1] * dv.y + acc[ct][2] * dv.z + acc[ct][3] * dv.w;
  }
#pragma unroll
  for (int h = 0; h < HEADS; ++h) {
    pS[h] += __shfl_xor(pS[h], 16);
    pS[h] += __shfl_xor(pS[h], 32);
    pD[h] += __shfl_xor(pD[h], 16);
    pD[h] += __shfl_xor(pD[h], 32);
  }
  if (lk == 0 && row < n) {
    if (HEADS == 4) {
      *(float4*)(aS + (size_t)row * 4) = make_float4(pS[0], pS[1], pS[2], pS[3]);
      *(float4*)(aD + (size_t)row * 4) = make_float4(pD[0], pD[1], pD[2], pD[3]);
    } else {
      aS[row] = pS[0];
      aD[row] = pD[0];
    }
  }

  // ---- XL store: 4 consecutive cols per lane -> packed uint2 ----
  if (row < n) {
    u32* Xp = (u32*)XL + (size_t)row * (COUT / 2);
#pragma unroll
    for (int ct = 0; ct < NT; ++ct) {
      *(uint2*)(Xp + ct * 8 + lk * 2) =
          make_uint2(pack2bf(acc[ct][0], acc[ct][1]), pack2bf(acc[ct][2], acc[ct][3]));
    }
  }
}

// ============ bucket-sort CSR build (unchanged) ============
#define PSTR 16  // padding stride (ints) for per-bucket counters

__global__ __launch_bounds__(256) void bucket_hist(const int* __restrict__ ei,
                                                   int* __restrict__ cntP,
                                                   int e4, int rem, int E, int NB) {
  int L = blockIdx.y;
  const int* dst = ei + (size_t)(2 * L + 1) * E;
  __shared__ int cnt[256];
  int t = threadIdx.x;
  cnt[t] = 0;
  __syncthreads();
  int gbase = blockIdx.x * 1024 + t;
#pragma unroll
  for (int u = 0; u < 4; ++u) {
    int g = gbase + u * 256;
    if (g < e4) {
      int4 d = *(const int4*)(dst + g * 4);
      atomicAdd(&cnt[d.x >> 8], 1);
      atomicAdd(&cnt[d.y >> 8], 1);
      atomicAdd(&cnt[d.z >> 8], 1);
      atomicAdd(&cnt[d.w >> 8], 1);
    }
  }
  if (blockIdx.x == 0 && t < rem) atomicAdd(&cnt[dst[e4 * 4 + t] >> 8], 1);
  __syncthreads();
  int c = cnt[t];
  if (t < NB && c > 0) atomicAdd(&cntP[(L * NB + t) * PSTR], c);
}

__global__ __launch_bounds__(256) void bucket_scan(const int* __restrict__ cntP,
                                                   int* __restrict__ bucketOff,
                                                   int* __restrict__ curP, int NB, int E) {
  int L = blockIdx.x;
  int t = threadIdx.x;
  int lane = t & 63, wid = t >> 6;
  __shared__ int wpart[4];
  int v = (t < NB) ? cntP[(L * NB + t) * PSTR] : 0;
  int inc = v;
#pragma unroll
  for (int off = 1; off < 64; off <<= 1) {
    int w = __shfl_up(inc, (unsigned)off, 64);
    if (lane >= off) inc += w;
  }
  if (lane == 63) wpart[wid] = inc;
  __syncthreads();
  if (t == 0) {
    int a = 0;
#pragma unroll
    for (int k = 0; k < 4; ++k) { int tmp = wpart[k]; wpart[k] = a; a += tmp; }
  }
  __syncthreads();
  int ex = wpart[wid] + inc - v;
  if (t < NB) {
    bucketOff[L * (NB + 1) + t] = ex;
    curP[(L * NB + t) * PSTR] = ex;
  }
  if (t == 0) bucketOff[L * (NB + 1) + NB] = E;
}

__global__ __launch_bounds__(256) void bucket_scatter(const int* __restrict__ ei,
                                                      int* __restrict__ curP,
                                                      int2* __restrict__ pairsAll,
                                                      int e4, int rem, int E, int NB) {
  int L = blockIdx.y;
  const int* src = ei + (size_t)(2 * L) * E;
  const int* dst = src + E;
  int2* pairs = pairsAll + (size_t)L * E;
  __shared__ int cnt[256];
  __shared__ int baseS[256];
  int t = threadIdx.x;
  cnt[t] = 0;
  __syncthreads();

  int gbase = blockIdx.x * 1024 + t;
  int4 dv[4], sv[4];
  bool val[4];
#pragma unroll
  for (int u = 0; u < 4; ++u) {
    int g = gbase + u * 256;
    val[u] = (g < e4);
    if (val[u]) {
      dv[u] = *(const int4*)(dst + g * 4);
      sv[u] = *(const int4*)(src + g * 4);
      atomicAdd(&cnt[dv[u].x >> 8], 1);
      atomicAdd(&cnt[dv[u].y >> 8], 1);
      atomicAdd(&cnt[dv[u].z >> 8], 1);
      atomicAdd(&cnt[dv[u].w >> 8], 1);
    }
  }
  int tailS = 0, tailD = 0;
  bool hasTail = (blockIdx.x == 0 && t < rem);
  if (hasTail) {
    tailD = dst[e4 * 4 + t];
    tailS = src[e4 * 4 + t];
    atomicAdd(&cnt[tailD >> 8], 1);
  }
  __syncthreads();
  int c = cnt[t];
  if (t < NB && c > 0) baseS[t] = atomicAdd(&curP[(L * NB + t) * PSTR], c);
  __syncthreads();
  cnt[t] = 0;  // reuse as local offset
  __syncthreads();
#pragma unroll
  for (int u = 0; u < 4; ++u) {
    if (val[u]) {
      int b, p;
      b = dv[u].x >> 8; p = atomicAdd(&cnt[b], 1); pairs[baseS[b] + p] = make_int2(sv[u].x, dv[u].x);
      b = dv[u].y >> 8; p = atomicAdd(&cnt[b], 1); pairs[baseS[b] + p] = make_int2(sv[u].y, dv[u].y);
      b = dv[u].z >> 8; p = atomicAdd(&cnt[b], 1); pairs[baseS[b] + p] = make_int2(sv[u].z, dv[u].z);
      b = dv[u].w >> 8; p = atomicAdd(&cnt[b], 1); pairs[baseS[b] + p] = make_int2(sv[u].w, dv[u].w);
    }
  }
  if (hasTail) {
    int b = tailD >> 8;
    int p = atomicAdd(&cnt[b], 1);
    pairs[baseS[b] + p] = make_int2(tailS, tailD);
  }
}

__global__ __launch_bounds__(256) void csr_finalize(const int2* __restrict__ pairsAll,
                                                    const int* __restrict__ bucketOff,
                                                    int* __restrict__ indptrAll,
                                                    int* __restrict__ srcIdxAll,
                                                    int N, int E, int NB) {
  int L = blockIdx.y, b = blockIdx.x;
  const int2* pairs = pairsAll + (size_t)L * E;
  int* indptr = indptrAll + (size_t)L * (N + 1);
  int* srcL = srcIdxAll + (size_t)L * (E + N);
  int base = b << 8;
  int nodes = min(256, N - base);
  int p0 = bucketOff[L * (NB + 1) + b];
  int p1 = bucketOff[L * (NB + 1) + b + 1];

  __shared__ int cnt[256];
  __shared__ int wpart[4];
  int t = threadIdx.x;
  int lane = t & 63, wid = t >> 6;
  cnt[t] = 0;
  __syncthreads();

  for (int i = p0 + t; i < p1; i += 256) atomicAdd(&cnt[pairs[i].y - base], 1);
  __syncthreads();

  int v = (t < nodes) ? cnt[t] + 1 : 0;
  int inc = v;
#pragma unroll
  for (int off = 1; off < 64; off <<= 1) {
    int w = __shfl_up(inc, (unsigned)off, 64);
    if (lane >= off) inc += w;
  }
  if (lane == 63) wpart[wid] = inc;
  __syncthreads();
  if (t == 0) {
    int a = 0;
#pragma unroll
    for (int k = 0; k < 4; ++k) { int tmp = wpart[k]; wpart[k] = a; a += tmp; }
  }
  __syncthreads();
  int ex = wpart[wid] + inc - v;
  __syncthreads();
  if (t < nodes) {
    int segStart = p0 + base + ex;
    indptr[base + t] = segStart;
    srcL[segStart] = base + t;
    cnt[t] = segStart + 1;
  }
  if (b == NB - 1 && t == 0) indptr[N] = E + N;
  __syncthreads();

  for (int i = p0 + t; i < p1; i += 256) {
    int2 pr = pairs[i];
    int p = atomicAdd(&cnt[pr.y - base], 1);
    srcL[p] = pr.x;
  }
}

// ---------- aggregation: wave = node, G edges per instruction (unchanged) ----------
template <int COUT, int HEADS, bool RELU>
__global__ __launch_bounds__(256) void aggregate(
    const u16* __restrict__ XL, const float* __restrict__ aS, const float* __restrict__ aD,
    const int* __restrict__ indptr, const int* __restrict__ srcIdx,
    const float* __restrict__ bias, float* __restrict__ outF, int n) {
  constexpr int VPL = 8;           // cols per lane
  constexpr int LPG = COUT / VPL;  // lanes per edge-group (16 or 8)
  constexpr int G = 64 / LPG;      // edges per batch (4 or 8)
  constexpr int C = COUT / HEADS;
  int wave = (blockIdx.x * blockDim.x + threadIdx.x) >> 6;
  if (wave >= n) return;
  int lane = threadIdx.x & 63;
  int g = lane / LPG;
  int cl = lane % LPG;
  int col0 = cl * VPL;
  int h = col0 / C;
  int i = wave;
  float ad = aD[i * HEADS + h];
  float s = 0.f;
  float acc[VPL];
#pragma unroll
  for (int v = 0; v < VPL; ++v) acc[v] = 0.f;
  int e0 = indptr[i], e1 = indptr[i + 1];
  const u32* XL32 = (const u32*)XL;

  auto doEdge = [&](int loadIdx, bool act) {
    int j = srcIdx[loadIdx];  // broadcast within group
    float a = aS[j * HEADS + h];
    uint4 px = *(const uint4*)(XL32 + j * (COUT / 2) + cl * 4);
    float l = a + ad;
    l = (l >= 0.f) ? l : 0.2f * l;
    float el = act ? __expf(fminf(l, 60.f)) : 0.f;
    s += el;
    acc[0] += el * bfbits(px.x << 16);
    acc[1] += el * bfbits(px.x & 0xffff0000u);
    acc[2] += el * bfbits(px.y << 16);
    acc[3] += el * bfbits(px.y & 0xffff0000u);
    acc[4] += el * bfbits(px.z << 16);
    acc[5] += el * bfbits(px.z & 0xffff0000u);
    acc[6] += el * bfbits(px.w << 16);
    acc[7] += el * bfbits(px.w & 0xffff0000u);
  };

  int idx = e0;
  for (; idx + 2 * G <= e1; idx += 2 * G) {
    doEdge(idx + g, true);
    doEdge(idx + G + g, true);
  }
  for (; idx + G <= e1; idx += G) doEdge(idx + g, true);
  int r = e1 - idx;
  if (r > 0) doEdge((g < r) ? (idx + g) : e0, g < r);

#pragma unroll
  for (int mk = LPG; mk < 64; mk <<= 1) {
    s += __shfl_xor(s, mk);
#pragma unroll
    for (int v = 0; v < VPL; ++v) acc[v] += __shfl_xor(acc[v], mk);
  }

  if (g == 0) {
    float inv = 1.f / (s + 1e-16f);
    float o[VPL];
#pragma unroll
    for (int v = 0; v < VPL; ++v) {
      o[v] = acc[v] * inv + bias[col0 + v];
      if (RELU) o[v] = fmaxf(o[v], 0.f);
    }
    float* op = outF + (size_t)i * COUT + col0;
    *(float4*)op = make_float4(o[0], o[1], o[2], o[3]);
    *(float4*)(op + 4) = make_float4(o[4], o[5], o[6], o[7]);
  }
}

extern "C" void kernel_launch(void* const* d_in, const int* in_sizes, int n_in,
                              void* d_out, int out_size, void* d_ws, size_t ws_size,
                              hipStream_t stream) {
  const float* x = (const float*)d_in[0];
  const int* ei = (const int*)d_in[1];
  const float* W1 = (const float*)d_in[2];
  const float* as1 = (const float*)d_in[3];
  const float* ad1 = (const float*)d_in[4];
  const float* b1 = (const float*)d_in[5];
  const float* W2 = (const float*)d_in[6];
  const float* as2 = (const float*)d_in[7];
  const float* ad2 = (const float*)d_in[8];
  const float* b2 = (const float*)d_in[9];
  const float* W3 = (const float*)d_in[10];
  const float* as3 = (const float*)d_in[11];
  const float* ad3 = (const float*)d_in[12];
  const float* b3 = (const float*)d_in[13];

  int N = in_sizes[0] / HID;  // x is [N,128]
  int E = in_sizes[1] / 6;    // edge_indices is [3,2,E]
  int NB = cdiv(N, 256);      // buckets of 256 nodes (NB <= 256 assumed)

  char* w = (char*)d_ws;
  auto alloc = [&](size_t bytes) {
    void* q = (void*)w;
    w += (bytes + 255) & ~(size_t)255;
    return q;
  };
  float* bufH = (float*)alloc((size_t)N * HID * 4);
  u16* bufXL = (u16*)alloc((size_t)N * HID * 2);
  float* aS = (float*)alloc((size_t)N * 4 * 4);
  float* aD = (float*)alloc((size_t)N * 4 * 4);
  u16* wt1 = (u16*)alloc((size_t)128 * 128 * 2);
  u16* wt2 = (u16*)alloc((size_t)128 * 128 * 2);
  u16* wt3 = (u16*)alloc((size_t)64 * 128 * 2);
  int* cntP = (int*)alloc((size_t)3 * NB * PSTR * 4);
  int* curP = (int*)alloc((size_t)3 * NB * PSTR * 4);
  int* bucketOff = (int*)alloc((size_t)3 * (NB + 1) * 4);
  int2* pairsAll = (int2*)alloc((size_t)3 * E * 8);
  int* indptrAll = (int*)alloc((size_t)3 * (N + 1) * 4);
  int* srcIdxAll = (int*)alloc((size_t)3 * (E + N) * 4);

  int e4 = E >> 2, rem = E & 3;
  int gx = cdiv(e4, 1024);  // 4096 edges per block

  // ---- W transpose + bf16 cast (tiny, L2-resident afterwards) ----
  prep_wt<<<64, 256, 0, stream>>>(W1, wt1, 128);
  prep_wt<<<64, 256, 0, stream>>>(W2, wt2, 128);
  prep_wt<<<32, 256, 0, stream>>>(W3, wt3, 64);

  // ---- CSR build for all 3 layers ----
  hipMemsetAsync(cntP, 0, (size_t)3 * NB * PSTR * 4, stream);
  {
    dim3 g(gx, 3);
    bucket_hist<<<g, 256, 0, stream>>>(ei, cntP, e4, rem, E, NB);
  }
  bucket_scan<<<3, 256, 0, stream>>>(cntP, bucketOff, curP, NB, E);
  {
    dim3 g(gx, 3);
    bucket_scatter<<<g, 256, 0, stream>>>(ei, curP, pairsAll, e4, rem, E, NB);
  }
  {
    dim3 g(NB, 3);
    csr_finalize<<<g, 256, 0, stream>>>(pairsAll, bucketOff, indptrAll, srcIdxAll, N, E, NB);
  }

  // ---- layer 1 ----
  gemm_attn_mfma<128, 4><<<cdiv(N, 64), 256, 0, stream>>>(x, wt1, as1, ad1, bufXL, aS, aD, N);
  aggregate<128, 4, true><<<cdiv(N, 4), 256, 0, stream>>>(
      bufXL, aS, aD, indptrAll, srcIdxAll, b1, bufH, N);
  // ---- layer 2 ----
  gemm_attn_mfma<128, 4><<<cdiv(N, 64), 256, 0, stream>>>(bufH, wt2, as2, ad2, bufXL, aS, aD, N);
  aggregate<128, 4, true><<<cdiv(N, 4), 256, 0, stream>>>(
      bufXL, aS, aD, indptrAll + (N + 1), srcIdxAll + (size_t)(E + N), b2, bufH, N);
  // ---- layer 3 ----
  gemm_attn_mfma<64, 1><<<cdiv(N, 64), 256, 0, stream>>>(bufH, wt3, as3, ad3, bufXL, aS, aD, N);
  aggregate<64, 1, false><<<cdiv(N, 4), 256, 0, stream>>>(
      bufXL, aS, aD, indptrAll + 2 * (N + 1), srcIdxAll + (size_t)2 * (E + N), b3,
      (float*)d_out, N);
}

// Round 2
// 317.212 us; speedup vs baseline: 1.0774x; 1.0247x over previous
//
#include <hip/hip_runtime.h>

typedef unsigned short u16;
typedef unsigned int u32;
typedef __attribute__((ext_vector_type(8))) short short8;
typedef __attribute__((ext_vector_type(4))) float f32x4;

#define HID 128

static inline int cdiv(long long a, int b) { return (int)((a + b - 1) / b); }

__device__ __forceinline__ float bfbits(u32 u) { union { u32 u; float f; } c; c.u = u; return c.f; }
__device__ __forceinline__ u16 f2bf(float f) {
  union { float f; u32 u; } c; c.f = f;
  u32 u = c.u;
  return (u16)((u + 0x7fffu + ((u >> 16) & 1u)) >> 16);  // RNE
}
__device__ __forceinline__ u32 pack2bf(float a, float b) {
  return (u32)f2bf(a) | ((u32)f2bf(b) << 16);
}

// ---------- W pre-transpose + bf16 cast for all 3 layers (1 launch) ----------
__global__ __launch_bounds__(256) void prep_wt3(
    const float* __restrict__ W1, const float* __restrict__ W2,
    const float* __restrict__ W3, u16* __restrict__ wt1, u16* __restrict__ wt2,
    u16* __restrict__ wt3) {
  int y = blockIdx.y;
  const float* W = (y == 0) ? W1 : ((y == 1) ? W2 : W3);
  u16* WT = (y == 0) ? wt1 : ((y == 1) ? wt2 : wt3);
  int cout = (y == 2) ? 64 : 128;
  int idx = blockIdx.x * 256 + threadIdx.x;
  if (idx < 128 * cout) {
    int k = idx / cout, c = idx - k * cout;
    WT[c * 128 + k] = f2bf(W[idx]);
  }
}

// ---------- MFMA GEMM + attention epilogue: no LDS, no barrier ----------
// H rows have ZERO inter-wave reuse -> each lane loads its own B-fragment
// straight from global (32B/row/K-step, exact-traffic). W^T is 32KB and
// L1-resident. Waves fully independent -> pure latency-hiding by occupancy.
// mfma(Wfrag, Hfrag) => acc[ct][r] = xl[node row][col=ct*16+lk*4+r].
template <int COUT, int HEADS>
__global__ __launch_bounds__(256) void gemm_attn_mfma(
    const float* __restrict__ Hin, const u16* __restrict__ WT,
    const float* __restrict__ attS, const float* __restrict__ attD,
    u16* __restrict__ XL, float* __restrict__ aS, float* __restrict__ aD, int n) {
  constexpr int NT = COUT / 16;    // col tiles (8 or 4)
  constexpr int C = COUT / HEADS;  // per-head channels
  constexpr int TPH = C / 16;      // tiles per head

  int t = threadIdx.x;
  int wv = t >> 6, ln = t & 63;
  int lrow = ln & 15;  // node-row within wave (= D col index)
  int lk = ln >> 4;    // k sub-chunk / D row-quad index
  int row = blockIdx.x * 64 + wv * 16 + lrow;
  bool ok = (row < n);
  int rowc = ok ? row : (n - 1);  // clamp: loads stay valid, stores guarded

  const float* hp = Hin + (size_t)rowc * HID;

  // hoist all 8 H loads (32B per lane per K-step) for memory-level parallelism
  float4 hv[8];
#pragma unroll
  for (int kb = 0; kb < 4; ++kb) {
    hv[2 * kb] = *(const float4*)(hp + kb * 32 + lk * 8);
    hv[2 * kb + 1] = *(const float4*)(hp + kb * 32 + lk * 8 + 4);
  }

  f32x4 acc[NT];
#pragma unroll
  for (int ct = 0; ct < NT; ++ct) acc[ct] = {0.f, 0.f, 0.f, 0.f};

#pragma unroll
  for (int kb = 0; kb < 4; ++kb) {
    union { short8 s; u32 u[4]; } bb;
    float4 h0 = hv[2 * kb], h1 = hv[2 * kb + 1];
    bb.u[0] = pack2bf(h0.x, h0.y);
    bb.u[1] = pack2bf(h0.z, h0.w);
    bb.u[2] = pack2bf(h1.x, h1.y);
    bb.u[3] = pack2bf(h1.z, h1.w);
    const u16* wp = WT + (size_t)lrow * HID + kb * 32 + lk * 8;
#pragma unroll
    for (int ct = 0; ct < NT; ++ct) {
      short8 aw = *(const short8*)(wp + (size_t)ct * 16 * HID);
      acc[ct] = __builtin_amdgcn_mfma_f32_16x16x32_bf16(aw, bb.s, acc[ct], 0, 0, 0);
    }
  }

  // ---- attention epilogue: per-row per-head dots from acc registers ----
  float pS[HEADS], pD[HEADS];
#pragma unroll
  for (int h = 0; h < HEADS; ++h) { pS[h] = 0.f; pD[h] = 0.f; }
#pragma unroll
  for (int ct = 0; ct < NT; ++ct) {
    float4 sv = *(const float4*)(attS + ct * 16 + lk * 4);
    float4 dv = *(const float4*)(attD + ct * 16 + lk * 4);
    int h = ct / TPH;
    pS[h] += acc[ct][0] * sv.x + acc[ct][1] * sv.y + acc[ct][2] * sv.z + acc[ct][3] * sv.w;
    pD[h] += acc[ct][0] * dv.x + acc[ct][1] * dv.y + acc[ct][2] * dv.z + acc[ct][3] * dv.w;
  }
#pragma unroll
  for (int h = 0; h < HEADS; ++h) {
    pS[h] += __shfl_xor(pS[h], 16);
    pS[h] += __shfl_xor(pS[h], 32);
    pD[h] += __shfl_xor(pD[h], 16);
    pD[h] += __shfl_xor(pD[h], 32);
  }
  if (lk == 0 && ok) {
    if (HEADS == 4) {
      *(float4*)(aS + (size_t)row * 4) = make_float4(pS[0], pS[1], pS[2], pS[3]);
      *(float4*)(aD + (size_t)row * 4) = make_float4(pD[0], pD[1], pD[2], pD[3]);
    } else {
      aS[row] = pS[0];
      aD[row] = pD[0];
    }
  }

  // ---- XL store: 4 consecutive cols per lane -> packed uint2 ----
  if (ok) {
    u32* Xp = (u32*)XL + (size_t)row * (COUT / 2);
#pragma unroll
    for (int ct = 0; ct < NT; ++ct) {
      *(uint2*)(Xp + ct * 8 + lk * 2) =
          make_uint2(pack2bf(acc[ct][0], acc[ct][1]), pack2bf(acc[ct][2], acc[ct][3]));
    }
  }
}

// ============ bucket-sort CSR build (unchanged) ============
#define PSTR 16  // padding stride (ints) for per-bucket counters

__global__ __launch_bounds__(256) void bucket_hist(const int* __restrict__ ei,
                                                   int* __restrict__ cntP,
                                                   int e4, int rem, int E, int NB) {
  int L = blockIdx.y;
  const int* dst = ei + (size_t)(2 * L + 1) * E;
  __shared__ int cnt[256];
  int t = threadIdx.x;
  cnt[t] = 0;
  __syncthreads();
  int gbase = blockIdx.x * 1024 + t;
#pragma unroll
  for (int u = 0; u < 4; ++u) {
    int g = gbase + u * 256;
    if (g < e4) {
      int4 d = *(const int4*)(dst + g * 4);
      atomicAdd(&cnt[d.x >> 8], 1);
      atomicAdd(&cnt[d.y >> 8], 1);
      atomicAdd(&cnt[d.z >> 8], 1);
      atomicAdd(&cnt[d.w >> 8], 1);
    }
  }
  if (blockIdx.x == 0 && t < rem) atomicAdd(&cnt[dst[e4 * 4 + t] >> 8], 1);
  __syncthreads();
  int c = cnt[t];
  if (t < NB && c > 0) atomicAdd(&cntP[(L * NB + t) * PSTR], c);
}

__global__ __launch_bounds__(256) void bucket_scan(const int* __restrict__ cntP,
                                                   int* __restrict__ bucketOff,
                                                   int* __restrict__ curP, int NB, int E) {
  int L = blockIdx.x;
  int t = threadIdx.x;
  int lane = t & 63, wid = t >> 6;
  __shared__ int wpart[4];
  int v = (t < NB) ? cntP[(L * NB + t) * PSTR] : 0;
  int inc = v;
#pragma unroll
  for (int off = 1; off < 64; off <<= 1) {
    int w = __shfl_up(inc, (unsigned)off, 64);
    if (lane >= off) inc += w;
  }
  if (lane == 63) wpart[wid] = inc;
  __syncthreads();
  if (t == 0) {
    int a = 0;
#pragma unroll
    for (int k = 0; k < 4; ++k) { int tmp = wpart[k]; wpart[k] = a; a += tmp; }
  }
  __syncthreads();
  int ex = wpart[wid] + inc - v;
  if (t < NB) {
    bucketOff[L * (NB + 1) + t] = ex;
    curP[(L * NB + t) * PSTR] = ex;
  }
  if (t == 0) bucketOff[L * (NB + 1) + NB] = E;
}

__global__ __launch_bounds__(256) void bucket_scatter(const int* __restrict__ ei,
                                                      int* __restrict__ curP,
                                                      int2* __restrict__ pairsAll,
                                                      int e4, int rem, int E, int NB) {
  int L = blockIdx.y;
  const int* src = ei + (size_t)(2 * L) * E;
  const int* dst = src + E;
  int2* pairs = pairsAll + (size_t)L * E;
  __shared__ int cnt[256];
  __shared__ int baseS[256];
  int t = threadIdx.x;
  cnt[t] = 0;
  __syncthreads();

  int gbase = blockIdx.x * 1024 + t;
  int4 dv[4], sv[4];
  bool val[4];
#pragma unroll
  for (int u = 0; u < 4; ++u) {
    int g = gbase + u * 256;
    val[u] = (g < e4);
    if (val[u]) {
      dv[u] = *(const int4*)(dst + g * 4);
      sv[u] = *(const int4*)(src + g * 4);
      atomicAdd(&cnt[dv[u].x >> 8], 1);
      atomicAdd(&cnt[dv[u].y >> 8], 1);
      atomicAdd(&cnt[dv[u].z >> 8], 1);
      atomicAdd(&cnt[dv[u].w >> 8], 1);
    }
  }
  int tailS = 0, tailD = 0;
  bool hasTail = (blockIdx.x == 0 && t < rem);
  if (hasTail) {
    tailD = dst[e4 * 4 + t];
    tailS = src[e4 * 4 + t];
    atomicAdd(&cnt[tailD >> 8], 1);
  }
  __syncthreads();
  int c = cnt[t];
  if (t < NB && c > 0) baseS[t] = atomicAdd(&curP[(L * NB + t) * PSTR], c);
  __syncthreads();
  cnt[t] = 0;  // reuse as local offset
  __syncthreads();
#pragma unroll
  for (int u = 0; u < 4; ++u) {
    if (val[u]) {
      int b, p;
      b = dv[u].x >> 8; p = atomicAdd(&cnt[b], 1); pairs[baseS[b] + p] = make_int2(sv[u].x, dv[u].x);
      b = dv[u].y >> 8; p = atomicAdd(&cnt[b], 1); pairs[baseS[b] + p] = make_int2(sv[u].y, dv[u].y);
      b = dv[u].z >> 8; p = atomicAdd(&cnt[b], 1); pairs[baseS[b] + p] = make_int2(sv[u].z, dv[u].z);
      b = dv[u].w >> 8; p = atomicAdd(&cnt[b], 1); pairs[baseS[b] + p] = make_int2(sv[u].w, dv[u].w);
    }
  }
  if (hasTail) {
    int b = tailD >> 8;
    int p = atomicAdd(&cnt[b], 1);
    pairs[baseS[b] + p] = make_int2(tailS, tailD);
  }
}

__global__ __launch_bounds__(256) void csr_finalize(const int2* __restrict__ pairsAll,
                                                    const int* __restrict__ bucketOff,
                                                    int* __restrict__ indptrAll,
                                                    int* __restrict__ srcIdxAll,
                                                    int N, int E, int NB) {
  int L = blockIdx.y, b = blockIdx.x;
  const int2* pairs = pairsAll + (size_t)L * E;
  int* indptr = indptrAll + (size_t)L * (N + 1);
  int* srcL = srcIdxAll + (size_t)L * (E + N);
  int base = b << 8;
  int nodes = min(256, N - base);
  int p0 = bucketOff[L * (NB + 1) + b];
  int p1 = bucketOff[L * (NB + 1) + b + 1];

  __shared__ int cnt[256];
  __shared__ int wpart[4];
  int t = threadIdx.x;
  int lane = t & 63, wid = t >> 6;
  cnt[t] = 0;
  __syncthreads();

  for (int i = p0 + t; i < p1; i += 256) atomicAdd(&cnt[pairs[i].y - base], 1);
  __syncthreads();

  int v = (t < nodes) ? cnt[t] + 1 : 0;
  int inc = v;
#pragma unroll
  for (int off = 1; off < 64; off <<= 1) {
    int w = __shfl_up(inc, (unsigned)off, 64);
    if (lane >= off) inc += w;
  }
  if (lane == 63) wpart[wid] = inc;
  __syncthreads();
  if (t == 0) {
    int a = 0;
#pragma unroll
    for (int k = 0; k < 4; ++k) { int tmp = wpart[k]; wpart[k] = a; a += tmp; }
  }
  __syncthreads();
  int ex = wpart[wid] + inc - v;
  __syncthreads();
  if (t < nodes) {
    int segStart = p0 + base + ex;
    indptr[base + t] = segStart;
    srcL[segStart] = base + t;
    cnt[t] = segStart + 1;
  }
  if (b == NB - 1 && t == 0) indptr[N] = E + N;
  __syncthreads();

  for (int i = p0 + t; i < p1; i += 256) {
    int2 pr = pairs[i];
    int p = atomicAdd(&cnt[pr.y - base], 1);
    srcL[p] = pr.x;
  }
}

// ---------- aggregation: wave = node, 8 edges/batch, preloaded src indices ----
// srcIdx for the node preloaded into one register/lane; per-batch j comes from
// __shfl (no memory dep) so the gather chain is ONE level (aS+XL in parallel).
// 2-deep ping-pong pipeline keeps ~2 batches of loads in flight.
template <int COUT, int HEADS, bool RELU>
__global__ __launch_bounds__(256) void aggregate(
    const u16* __restrict__ XL, const float* __restrict__ aS, const float* __restrict__ aD,
    const int* __restrict__ indptr, const int* __restrict__ srcIdx,
    const float* __restrict__ bias, float* __restrict__ outF, int n) {
  constexpr int LPG = 8;           // lanes per edge
  constexpr int G = 8;             // edges per batch
  constexpr int VPL = COUT / LPG;  // cols per lane (16 or 8)
  constexpr int U32PL = VPL / 2;   // u32 per lane (8 or 4)
  constexpr int C = COUT / HEADS;
  int wave = (blockIdx.x * blockDim.x + threadIdx.x) >> 6;
  if (wave >= n) return;
  int lane = threadIdx.x & 63;
  int g = lane >> 3;
  int cl = lane & 7;
  int col0 = cl * VPL;
  int h = col0 / C;
  int i = wave;
  float ad = aD[(size_t)i * HEADS + h];
  int e0 = indptr[i], e1 = indptr[i + 1];
  int deg = e1 - e0;  // >= 1 (self-loop)
  int jreg = srcIdx[e0 + min(lane, deg - 1)];  // first 64 src indices, coalesced

  float s = 0.f;
  float acc[VPL];
#pragma unroll
  for (int v = 0; v < VPL; ++v) acc[v] = 0.f;
  const u32* XL32 = (const u32*)XL;

  auto fetch = [&](int b, float& av, uint4& q0, uint4& q1, bool& act) {
    int k0 = b * G + g;
    act = (k0 < deg);
    int k = act ? k0 : 0;
    int js = __shfl(jreg, min(k, 63));
    if (k >= 64) js = srcIdx[e0 + k];  // never for this data; correctness net
    av = aS[(size_t)js * HEADS + h];
    const u32* xp = XL32 + (size_t)js * (COUT / 2) + cl * U32PL;
    q0 = *(const uint4*)xp;
    if (U32PL == 8) q1 = *(const uint4*)(xp + 4);
  };
  auto consume = [&](float av, const uint4& q0, const uint4& q1, bool act) {
    float l = av + ad;
    l = (l >= 0.f) ? l : 0.2f * l;
    float el = act ? __expf(fminf(l, 60.f)) : 0.f;
    s += el;
    acc[0] += el * bfbits(q0.x << 16);
    acc[1] += el * bfbits(q0.x & 0xffff0000u);
    acc[2] += el * bfbits(q0.y << 16);
    acc[3] += el * bfbits(q0.y & 0xffff0000u);
    acc[4] += el * bfbits(q0.z << 16);
    acc[5] += el * bfbits(q0.z & 0xffff0000u);
    acc[6] += el * bfbits(q0.w << 16);
    acc[7] += el * bfbits(q0.w & 0xffff0000u);
    if (U32PL == 8) {
      acc[VPL - 8] += el * bfbits(q1.x << 16);   // VPL==16 path
      acc[VPL - 7] += el * bfbits(q1.x & 0xffff0000u);
      acc[VPL - 6] += el * bfbits(q1.y << 16);
      acc[VPL - 5] += el * bfbits(q1.y & 0xffff0000u);
      acc[VPL - 4] += el * bfbits(q1.z << 16);
      acc[VPL - 3] += el * bfbits(q1.z & 0xffff0000u);
      acc[VPL - 2] += el * bfbits(q1.w << 16);
      acc[VPL - 1] += el * bfbits(q1.w & 0xffff0000u);
    }
  };

  int nb = (deg + G - 1) / G;
  float aa, ab;
  uint4 pa0 = make_uint4(0, 0, 0, 0), pa1 = pa0, pb0 = pa0, pb1 = pa0;
  bool acta, actb;
  fetch(0, aa, pa0, pa1, acta);
  for (int b = 0; b < nb; b += 2) {
    if (b + 1 < nb) {
      fetch(b + 1, ab, pb0, pb1, actb);
      consume(aa, pa0, pa1, acta);
      if (b + 2 < nb) fetch(b + 2, aa, pa0, pa1, acta);
      consume(ab, pb0, pb1, actb);
    } else {
      consume(aa, pa0, pa1, acta);
    }
  }

#pragma unroll
  for (int mk = LPG; mk < 64; mk <<= 1) {
    s += __shfl_xor(s, mk);
#pragma unroll
    for (int v = 0; v < VPL; ++v) acc[v] += __shfl_xor(acc[v], mk);
  }

  if (g == 0) {
    float inv = 1.f / (s + 1e-16f);
    float o[VPL];
#pragma unroll
    for (int v = 0; v < VPL; ++v) {
      o[v] = acc[v] * inv + bias[col0 + v];
      if (RELU) o[v] = fmaxf(o[v], 0.f);
    }
    float* op = outF + (size_t)i * COUT + col0;
#pragma unroll
    for (int v4 = 0; v4 < VPL / 4; ++v4)
      *(float4*)(op + v4 * 4) = make_float4(o[v4 * 4], o[v4 * 4 + 1], o[v4 * 4 + 2], o[v4 * 4 + 3]);
  }
}

extern "C" void kernel_launch(void* const* d_in, const int* in_sizes, int n_in,
                              void* d_out, int out_size, void* d_ws, size_t ws_size,
                              hipStream_t stream) {
  const float* x = (const float*)d_in[0];
  const int* ei = (const int*)d_in[1];
  const float* W1 = (const float*)d_in[2];
  const float* as1 = (const float*)d_in[3];
  const float* ad1 = (const float*)d_in[4];
  const float* b1 = (const float*)d_in[5];
  const float* W2 = (const float*)d_in[6];
  const float* as2 = (const float*)d_in[7];
  const float* ad2 = (const float*)d_in[8];
  const float* b2 = (const float*)d_in[9];
  const float* W3 = (const float*)d_in[10];
  const float* as3 = (const float*)d_in[11];
  const float* ad3 = (const float*)d_in[12];
  const float* b3 = (const float*)d_in[13];

  int N = in_sizes[0] / HID;  // x is [N,128]
  int E = in_sizes[1] / 6;    // edge_indices is [3,2,E]
  int NB = cdiv(N, 256);      // buckets of 256 nodes (NB <= 256 assumed)

  char* w = (char*)d_ws;
  auto alloc = [&](size_t bytes) {
    void* q = (void*)w;
    w += (bytes + 255) & ~(size_t)255;
    return q;
  };
  float* bufH = (float*)alloc((size_t)N * HID * 4);
  u16* bufXL = (u16*)alloc((size_t)N * HID * 2);
  float* aS = (float*)alloc((size_t)N * 4 * 4);
  float* aD = (float*)alloc((size_t)N * 4 * 4);
  u16* wt1 = (u16*)alloc((size_t)128 * 128 * 2);
  u16* wt2 = (u16*)alloc((size_t)128 * 128 * 2);
  u16* wt3 = (u16*)alloc((size_t)64 * 128 * 2);
  int* cntP = (int*)alloc((size_t)3 * NB * PSTR * 4);
  int* curP = (int*)alloc((size_t)3 * NB * PSTR * 4);
  int* bucketOff = (int*)alloc((size_t)3 * (NB + 1) * 4);
  int2* pairsAll = (int2*)alloc((size_t)3 * E * 8);
  int* indptrAll = (int*)alloc((size_t)3 * (N + 1) * 4);
  int* srcIdxAll = (int*)alloc((size_t)3 * (E + N) * 4);

  int e4 = E >> 2, rem = E & 3;
  int gx = cdiv(e4, 1024);  // 4096 edges per block

  // ---- W transpose + bf16 cast (one launch; L2-resident afterwards) ----
  {
    dim3 g(64, 3);
    prep_wt3<<<g, 256, 0, stream>>>(W1, W2, W3, wt1, wt2, wt3);
  }

  // ---- CSR build for all 3 layers ----
  hipMemsetAsync(cntP, 0, (size_t)3 * NB * PSTR * 4, stream);
  {
    dim3 g(gx, 3);
    bucket_hist<<<g, 256, 0, stream>>>(ei, cntP, e4, rem, E, NB);
  }
  bucket_scan<<<3, 256, 0, stream>>>(cntP, bucketOff, curP, NB, E);
  {
    dim3 g(gx, 3);
    bucket_scatter<<<g, 256, 0, stream>>>(ei, curP, pairsAll, e4, rem, E, NB);
  }
  {
    dim3 g(NB, 3);
    csr_finalize<<<g, 256, 0, stream>>>(pairsAll, bucketOff, indptrAll, srcIdxAll, N, E, NB);
  }

  // ---- layer 1 ----
  gemm_attn_mfma<128, 4><<<cdiv(N, 64), 256, 0, stream>>>(x, wt1, as1, ad1, bufXL, aS, aD, N);
  aggregate<128, 4, true><<<cdiv(N, 4), 256, 0, stream>>>(
      bufXL, aS, aD, indptrAll, srcIdxAll, b1, bufH, N);
  // ---- layer 2 ----
  gemm_attn_mfma<128, 4><<<cdiv(N, 64), 256, 0, stream>>>(bufH, wt2, as2, ad2, bufXL, aS, aD, N);
  aggregate<128, 4, true><<<cdiv(N, 4), 256, 0, stream>>>(
      bufXL, aS, aD, indptrAll + (N + 1), srcIdxAll + (size_t)(E + N), b2, bufH, N);
  // ---- layer 3 ----
  gemm_attn_mfma<64, 1><<<cdiv(N, 64), 256, 0, stream>>>(bufH, wt3, as3, ad3, bufXL, aS, aD, N);
  aggregate<64, 1, false><<<cdiv(N, 4), 256, 0, stream>>>(
      bufXL, aS, aD, indptrAll + 2 * (N + 1), srcIdxAll + (size_t)2 * (E + N), b3,
      (float*)d_out, N);
}